// Round 1
// baseline (550.985 us; speedup 1.0000x reference)
//
#include <hip/hip_runtime.h>
#include <hip/hip_bf16.h>

using bf16 = __hip_bfloat16;
typedef __bf16 v8bf __attribute__((ext_vector_type(8)));
typedef float v4f __attribute__((ext_vector_type(4)));

#define H_ 1024
#define A_ 16
#define O_ 4
#define B_ 4096
#define P_ 2048
#define EPS_ 1e-5f

// async global->LDS, 16B per lane; lds pointer must be wave-uniform base.
__device__ __forceinline__ void gl_lds16(const void* g, void* l) {
    __builtin_amdgcn_global_load_lds(
        (const __attribute__((address_space(1))) void*)g,
        (__attribute__((address_space(3))) void*)l, 16, 0, 0);
}

// ---- b12 = b1 + b2 -------------------------------------------------------
__global__ void addbias_k(const float* __restrict__ b1, const float* __restrict__ b2,
                          float* __restrict__ b12, int n) {
    int i = blockIdx.x * 256 + threadIdx.x;
    if (i < n) b12[i] = b1[i] + b2[i];
}

// ---- gather selected rows of X,X1 -> XX[p][0:H]=X, [H:2H]=X1 (bf16) ------
__global__ __launch_bounds__(256) void gather_k(const float* __restrict__ X,
                                                const float* __restrict__ X1,
                                                const int* __restrict__ pos,
                                                bf16* __restrict__ XX) {
    int p = blockIdx.x;
    int row = pos[p];
    const float4* x  = (const float4*)(X  + (size_t)row * H_);
    const float4* x1 = (const float4*)(X1 + (size_t)row * H_);
    bf16* o = XX + (size_t)p * (2 * H_);
    int i = threadIdx.x;  // 0..255, H/4 = 256
    float4 v = x[i];
    o[i * 4 + 0] = __float2bfloat16(v.x);
    o[i * 4 + 1] = __float2bfloat16(v.y);
    o[i * 4 + 2] = __float2bfloat16(v.z);
    o[i * 4 + 3] = __float2bfloat16(v.w);
    float4 w = x1[i];
    o[H_ + i * 4 + 0] = __float2bfloat16(w.x);
    o[H_ + i * 4 + 1] = __float2bfloat16(w.y);
    o[H_ + i * 4 + 2] = __float2bfloat16(w.z);
    o[H_ + i * 4 + 3] = __float2bfloat16(w.w);
}

// ---- transpose + fp32->bf16: src[a][K][N] -> dst[a][N][dstK] at kOff ------
__global__ __launch_bounds__(256) void transpose_conv_k(const float* __restrict__ src,
                                                        bf16* __restrict__ dst,
                                                        int K, int N, int dstK, int kOff) {
    __shared__ float tile[32][33];
    int a = blockIdx.z;
    int k0 = blockIdx.x * 32;
    int n0 = blockIdx.y * 32;
    const float* s = src + (size_t)a * K * N;
    int tc = threadIdx.x & 31;
    int tr = threadIdx.x >> 5;  // 0..7
#pragma unroll
    for (int r = 0; r < 32; r += 8)
        tile[tr + r][tc] = s[(size_t)(k0 + tr + r) * N + n0 + tc];
    __syncthreads();
    bf16* d = dst + (size_t)a * N * dstK;
#pragma unroll
    for (int r = 0; r < 32; r += 8) {
        int n = n0 + tr + r;
        int k = k0 + tc;
        d[(size_t)n * dstK + kOff + k] = __float2bfloat16(tile[tc][tr + r]);
    }
}

// ---- m97-style bf16 GEMM: C[a][M][N] = A[a][M][K] @ Bt[a][N][K]^T + bias --
template <bool RELU>
__global__ __launch_bounds__(256) void gemm_bt(const bf16* __restrict__ Amat, size_t aStrideA,
                                               const bf16* __restrict__ Bt,
                                               const float* __restrict__ bias,
                                               bf16* __restrict__ C,
                                               int M, int N, int K) {
    constexpr int BM = 128, BN = 128, BK = 32;
    __shared__ __align__(16) unsigned short As[BM * BK];
    __shared__ __align__(16) unsigned short Bs[BN * BK];

    const int a = blockIdx.z;
    const bf16* Ab = Amat + (size_t)a * aStrideA;
    const bf16* Bb = Bt + (size_t)a * (size_t)N * K;
    const int bm = blockIdx.x, bn = blockIdx.y;
    const int tid = threadIdx.x;
    const int lane = tid & 63;
    const int wave = tid >> 6;
    const int wm = (wave & 1) * 64;  // wave 2x2 grid over 128x128 tile
    const int wn = (wave >> 1) * 64;

    v4f acc[4][4];
#pragma unroll
    for (int i = 0; i < 4; i++)
#pragma unroll
        for (int j = 0; j < 4; j++) acc[i][j] = (v4f){0.f, 0.f, 0.f, 0.f};

    // staging: slot idx = tid (issue0 rows 0..63) / 256+tid (issue1 rows 64..127)
    const int r0 = tid >> 2;
    const int c0 = (tid & 3) * 8;
    const bf16* agBase = Ab + (size_t)(bm * BM + r0) * K + c0;
    const bf16* bgBase = Bb + (size_t)(bn * BN + r0) * K + c0;
    unsigned short* aLds0 = As + wave * 512;           // wave-uniform bases
    unsigned short* aLds1 = As + 2048 + wave * 512;
    unsigned short* bLds0 = Bs + wave * 512;
    unsigned short* bLds1 = Bs + 2048 + wave * 512;
    const size_t rowSkip = (size_t)64 * K;

    const int kq = (lane >> 4) * 8;
    const int lr = lane & 15;

    for (int k0 = 0; k0 < K; k0 += BK) {
        gl_lds16(agBase + k0, aLds0);
        gl_lds16(agBase + k0 + rowSkip, aLds1);
        gl_lds16(bgBase + k0, bLds0);
        gl_lds16(bgBase + k0 + rowSkip, bLds1);
        __syncthreads();  // drains vmcnt -> LDS tiles ready
        v8bf af[4], bfr[4];
#pragma unroll
        for (int mi = 0; mi < 4; mi++)
            af[mi] = *(const v8bf*)(As + (wm + mi * 16 + lr) * BK + kq);
#pragma unroll
        for (int ni = 0; ni < 4; ni++)
            bfr[ni] = *(const v8bf*)(Bs + (wn + ni * 16 + lr) * BK + kq);
#pragma unroll
        for (int mi = 0; mi < 4; mi++)
#pragma unroll
            for (int ni = 0; ni < 4; ni++)
                acc[mi][ni] = __builtin_amdgcn_mfma_f32_16x16x32_bf16(af[mi], bfr[ni],
                                                                      acc[mi][ni], 0, 0, 0);
        __syncthreads();
    }

    // epilogue: C/D layout col=lane&15, row=(lane>>4)*4+reg
    const int lq = lane >> 4;
    bf16* Cb = C + (size_t)a * M * N;
#pragma unroll
    for (int ni = 0; ni < 4; ni++) {
        const int col = bn * BN + wn + ni * 16 + lr;
        const float bv = bias[(size_t)a * N + col];
#pragma unroll
        for (int mi = 0; mi < 4; mi++) {
            const int row0 = bm * BM + wm + mi * 16 + lq * 4;
#pragma unroll
            for (int rg = 0; rg < 4; rg++) {
                float v = acc[mi][ni][rg] + bv;
                if (RELU) v = v > 0.f ? v : 0.f;
                Cb[(size_t)(row0 + rg) * N + col] = __float2bfloat16(v);
            }
        }
    }
}

// ---- fused LayerNorm + [H]->[O] head: one wave per (a,p) row --------------
__global__ __launch_bounds__(256) void ln_head_k(const bf16* __restrict__ Hb,  // [A][P][H]
                                                 const float* __restrict__ gamma,
                                                 const float* __restrict__ beta,
                                                 const float* __restrict__ W4,  // [A][H][O]
                                                 const float* __restrict__ b4,  // [A][O]
                                                 float* __restrict__ out) {     // [P][A*O]
    int w = blockIdx.x * 4 + (threadIdx.x >> 6);
    int lane = threadIdx.x & 63;
    int a = w >> 11;    // / P_
    int p = w & (P_ - 1);
    const bf16* hrow = Hb + ((size_t)a * P_ + p) * H_;
    float hv[16];
    float s = 0.f, ss = 0.f;
#pragma unroll
    for (int i = 0; i < 16; i++) {
        float v = __bfloat162float(hrow[lane + i * 64]);
        hv[i] = v;
        s += v;
        ss += v * v;
    }
#pragma unroll
    for (int off = 32; off; off >>= 1) {
        s += __shfl_xor(s, off);
        ss += __shfl_xor(ss, off);
    }
    float mu = s * (1.f / H_);
    float var = ss * (1.f / H_) - mu * mu;
    float rstd = rsqrtf(var + EPS_);
    const float* g = gamma + (size_t)a * H_;
    const float* be = beta + (size_t)a * H_;
    const float4* w4 = (const float4*)(W4 + (size_t)a * H_ * O_);
    float a0 = 0.f, a1 = 0.f, a2 = 0.f, a3 = 0.f;
#pragma unroll
    for (int i = 0; i < 16; i++) {
        int k = lane + i * 64;
        float hn = (hv[i] - mu) * rstd * g[k] + be[k];
        float4 wv = w4[k];
        a0 += hn * wv.x;
        a1 += hn * wv.y;
        a2 += hn * wv.z;
        a3 += hn * wv.w;
    }
#pragma unroll
    for (int off = 32; off; off >>= 1) {
        a0 += __shfl_xor(a0, off);
        a1 += __shfl_xor(a1, off);
        a2 += __shfl_xor(a2, off);
        a3 += __shfl_xor(a3, off);
    }
    if (lane < 4) {
        float v = (lane == 0 ? a0 : lane == 1 ? a1 : lane == 2 ? a2 : a3) + b4[a * O_ + lane];
        out[(size_t)p * (A_ * O_) + a * O_ + lane] = v;
    }
}

extern "C" void kernel_launch(void* const* d_in, const int* in_sizes, int n_in,
                              void* d_out, int out_size, void* d_ws, size_t ws_size,
                              hipStream_t stream) {
    const float* X     = (const float*)d_in[0];
    const float* X1    = (const float*)d_in[1];
    const float* W1    = (const float*)d_in[2];
    const float* b1    = (const float*)d_in[3];
    const float* W2    = (const float*)d_in[4];
    const float* b2    = (const float*)d_in[5];
    const float* W3    = (const float*)d_in[6];
    const float* b3    = (const float*)d_in[7];
    const float* gamma = (const float*)d_in[8];
    const float* beta  = (const float*)d_in[9];
    const float* W4    = (const float*)d_in[10];
    const float* b4    = (const float*)d_in[11];
    const int* pos     = (const int*)d_in[12];
    float* out = (float*)d_out;

    char* ws = (char*)d_ws;
    bf16* XX   = (bf16*)(ws);                          // P*2H bf16   = 8 MB
    bf16* Z    = (bf16*)(ws + ((size_t)8 << 20));      // A*P*H bf16  = 64 MB
    bf16* WT3  = (bf16*)(ws + ((size_t)72 << 20));     // A*H*H bf16  = 32 MB
    bf16* WT12 = (bf16*)(ws + ((size_t)104 << 20));    // A*H*2H bf16 = 64 MB (dead after gemm1)
    float* b12 = (float*)(ws + ((size_t)168 << 20));   // A*H fp32    = 64 KB
    bf16* Hb   = WT12;                                 // alias: written by gemm2 after WT12 is dead

    addbias_k<<<(A_ * H_ + 255) / 256, 256, 0, stream>>>(b1, b2, b12, A_ * H_);
    gather_k<<<P_, 256, 0, stream>>>(X, X1, pos, XX);
    dim3 tgrid(H_ / 32, H_ / 32, A_);
    transpose_conv_k<<<tgrid, 256, 0, stream>>>(W1, WT12, H_, H_, 2 * H_, 0);
    transpose_conv_k<<<tgrid, 256, 0, stream>>>(W2, WT12, H_, H_, 2 * H_, H_);
    transpose_conv_k<<<tgrid, 256, 0, stream>>>(W3, WT3, H_, H_, H_, 0);

    dim3 g1(P_ / 128, H_ / 128, A_);
    // z = [X|X1] @ [W1;W2]^T + (b1+b2)   (K = 2H, A-matrix shared across a)
    gemm_bt<false><<<g1, 256, 0, stream>>>(XX, 0, WT12, b12, Z, P_, H_, 2 * H_);
    // h = relu(z @ W3^T + b3)            (K = H, A-matrix batched over a)
    gemm_bt<true><<<g1, 256, 0, stream>>>(Z, (size_t)P_ * H_, WT3, b3, Hb, P_, H_, H_);

    ln_head_k<<<P_ * A_ / 4, 256, 0, stream>>>(Hb, gamma, beta, W4, b4, out);
}

// Round 2
// 549.905 us; speedup vs baseline: 1.0020x; 1.0020x over previous
//
#include <hip/hip_runtime.h>
#include <hip/hip_bf16.h>

using bf16 = __hip_bfloat16;
typedef __bf16 v8bf __attribute__((ext_vector_type(8)));
typedef float v4f __attribute__((ext_vector_type(4)));

#define H_ 1024
#define A_ 16
#define O_ 4
#define B_ 4096
#define P_ 2048
#define EPS_ 1e-5f

// async global->LDS, 16B per lane; lds pointer must be wave-uniform base.
__device__ __forceinline__ void gl_lds16(const void* g, void* l) {
    __builtin_amdgcn_global_load_lds(
        (const __attribute__((address_space(1))) void*)g,
        (__attribute__((address_space(3))) void*)l, 16, 0, 0);
}

// ---- b12 = b1 + b2 -------------------------------------------------------
__global__ void addbias_k(const float* __restrict__ b1, const float* __restrict__ b2,
                          float* __restrict__ b12, int n) {
    int i = blockIdx.x * 256 + threadIdx.x;
    if (i < n) b12[i] = b1[i] + b2[i];
}

// ---- gather selected rows of X,X1 -> XX[p][0:H]=X, [H:2H]=X1 (bf16) ------
__global__ __launch_bounds__(256) void gather_k(const float* __restrict__ X,
                                                const float* __restrict__ X1,
                                                const int* __restrict__ pos,
                                                bf16* __restrict__ XX) {
    int p = blockIdx.x;
    int row = pos[p];
    const float4* x  = (const float4*)(X  + (size_t)row * H_);
    const float4* x1 = (const float4*)(X1 + (size_t)row * H_);
    bf16* o = XX + (size_t)p * (2 * H_);
    int i = threadIdx.x;  // 0..255, H/4 = 256
    float4 v = x[i];
    __align__(8) bf16 t[4];
    t[0] = __float2bfloat16(v.x); t[1] = __float2bfloat16(v.y);
    t[2] = __float2bfloat16(v.z); t[3] = __float2bfloat16(v.w);
    *(uint2*)(o + i * 4) = *(const uint2*)t;
    float4 w = x1[i];
    t[0] = __float2bfloat16(w.x); t[1] = __float2bfloat16(w.y);
    t[2] = __float2bfloat16(w.z); t[3] = __float2bfloat16(w.w);
    *(uint2*)(o + H_ + i * 4) = *(const uint2*)t;
}

// ---- merged transpose+convert for W1,W2,W3 --------------------------------
// which = z>>4: 0 -> W1 into WT12[:, 0:1024], 1 -> W2 into WT12[:, 1024:2048],
//               2 -> W3 into WT3.  src[a][K][N] fp32 -> dst[a][N][dstK] bf16.
__global__ __launch_bounds__(256) void transpose3_k(const float* __restrict__ W1s,
                                                    const float* __restrict__ W2s,
                                                    const float* __restrict__ W3s,
                                                    bf16* __restrict__ WT12,
                                                    bf16* __restrict__ WT3) {
    __shared__ float tile[64][65];
    const int which = blockIdx.z >> 4;
    const int a = blockIdx.z & 15;
    const float* src = (which == 0) ? W1s : (which == 1) ? W2s : W3s;
    bf16* dstBase = (which == 2) ? WT3 : WT12;
    const int dstK = (which == 2) ? H_ : 2 * H_;
    const int kOff = (which == 1) ? H_ : 0;

    const int k0 = blockIdx.x * 64;
    const int n0 = blockIdx.y * 64;
    const float* s = src + (size_t)a * H_ * H_;
    const int tc = threadIdx.x & 15;   // float4 column
    const int tr = threadIdx.x >> 4;   // 0..15
#pragma unroll
    for (int r = 0; r < 64; r += 16) {
        float4 v = *(const float4*)(s + (size_t)(k0 + tr + r) * H_ + n0 + tc * 4);
        tile[tr + r][tc * 4 + 0] = v.x;
        tile[tr + r][tc * 4 + 1] = v.y;
        tile[tr + r][tc * 4 + 2] = v.z;
        tile[tr + r][tc * 4 + 3] = v.w;
    }
    __syncthreads();
    bf16* d = dstBase + (size_t)a * H_ * dstK + kOff;
    const int wc = threadIdx.x & 7;   // k-chunk of 8
    const int wr = threadIdx.x >> 3;  // 0..31
#pragma unroll
    for (int r = 0; r < 64; r += 32) {
        const int n = wr + r;
        __align__(16) bf16 tmp[8];
#pragma unroll
        for (int j = 0; j < 8; j++) tmp[j] = __float2bfloat16(tile[wc * 8 + j][n]);
        *(uint4*)(d + (size_t)(n0 + n) * dstK + k0 + wc * 8) = *(const uint4*)tmp;
    }
}

// ---- m97-style bf16 GEMM: C[a][M][N] = A[a][M][K] @ Bt[a][N][K]^T + bias --
// LDS tiles use a 16B-chunk XOR swizzle: slot (r, c) holds global chunk
// c ^ ((r>>1)&3), so each 8-lane phase of ds_read_b128 covers all 32 banks.
template <bool RELU>
__global__ __launch_bounds__(256) void gemm_bt(const bf16* __restrict__ Amat, size_t aStrideA,
                                               const bf16* __restrict__ Bt,
                                               const float* __restrict__ bias,
                                               bf16* __restrict__ C,
                                               int M, int N, int K) {
    constexpr int BM = 128, BN = 128, BK = 32;
    __shared__ __align__(16) unsigned short As[BM * BK];
    __shared__ __align__(16) unsigned short Bs[BN * BK];

    const int a = blockIdx.z;
    const bf16* Ab = Amat + (size_t)a * aStrideA;
    const bf16* Bb = Bt + (size_t)a * (size_t)N * K;
    const int bm = blockIdx.x, bn = blockIdx.y;
    const int tid = threadIdx.x;
    const int lane = tid & 63;
    const int wave = tid >> 6;
    const int wm = (wave & 1) * 64;  // wave 2x2 grid over 128x128 tile
    const int wn = (wave >> 1) * 64;

    v4f acc[4][4];
#pragma unroll
    for (int i = 0; i < 4; i++)
#pragma unroll
        for (int j = 0; j < 4; j++) acc[i][j] = (v4f){0.f, 0.f, 0.f, 0.f};

    // staging: lane's fixed LDS slot = row r0, chunk (tid&3); it loads the
    // swizzled global chunk so slot c holds global chunk c ^ ((r0>>1)&3).
    const int r0 = tid >> 2;
    const int cs = (((tid & 3) ^ ((r0 >> 1) & 3))) * 8;   // swizzled source chunk
    const bf16* agBase = Ab + (size_t)(bm * BM + r0) * K + cs;
    const bf16* bgBase = Bb + (size_t)(bn * BN + r0) * K + cs;
    unsigned short* aLds0 = As + wave * 512;           // wave-uniform bases
    unsigned short* aLds1 = As + 2048 + wave * 512;
    unsigned short* bLds0 = Bs + wave * 512;
    unsigned short* bLds1 = Bs + 2048 + wave * 512;
    const size_t rowSkip = (size_t)64 * K;

    const int lr = lane & 15;
    const int q = lane >> 4;
    const int kq = (q ^ ((lr >> 1) & 3)) * 8;  // swizzled read chunk -> logical chunk q

    for (int k0 = 0; k0 < K; k0 += BK) {
        gl_lds16(agBase + k0, aLds0);
        gl_lds16(agBase + k0 + rowSkip, aLds1);
        gl_lds16(bgBase + k0, bLds0);
        gl_lds16(bgBase + k0 + rowSkip, bLds1);
        __syncthreads();  // drains vmcnt -> LDS tiles ready
        v8bf af[4], bfr[4];
#pragma unroll
        for (int mi = 0; mi < 4; mi++)
            af[mi] = *(const v8bf*)(As + (wm + mi * 16 + lr) * BK + kq);
#pragma unroll
        for (int ni = 0; ni < 4; ni++)
            bfr[ni] = *(const v8bf*)(Bs + (wn + ni * 16 + lr) * BK + kq);
#pragma unroll
        for (int mi = 0; mi < 4; mi++)
#pragma unroll
            for (int ni = 0; ni < 4; ni++)
                acc[mi][ni] = __builtin_amdgcn_mfma_f32_16x16x32_bf16(af[mi], bfr[ni],
                                                                      acc[mi][ni], 0, 0, 0);
        __syncthreads();
    }

    // epilogue: C/D layout col=lane&15, row=(lane>>4)*4+reg
    const int lq = lane >> 4;
    bf16* Cb = C + (size_t)a * M * N;
#pragma unroll
    for (int ni = 0; ni < 4; ni++) {
        const int col = bn * BN + wn + ni * 16 + lr;
        const float bv = bias[(size_t)a * N + col];
#pragma unroll
        for (int mi = 0; mi < 4; mi++) {
            const int row0 = bm * BM + wm + mi * 16 + lq * 4;
#pragma unroll
            for (int rg = 0; rg < 4; rg++) {
                float v = acc[mi][ni][rg] + bv;
                if (RELU) v = v > 0.f ? v : 0.f;
                Cb[(size_t)(row0 + rg) * N + col] = __float2bfloat16(v);
            }
        }
    }
}

// ---- fused LayerNorm + [H]->[O] head: one wave per (a,p) row --------------
__global__ __launch_bounds__(256) void ln_head_k(const bf16* __restrict__ Hb,  // [A][P][H]
                                                 const float* __restrict__ gamma,
                                                 const float* __restrict__ beta,
                                                 const float* __restrict__ W4,  // [A][H][O]
                                                 const float* __restrict__ b4,  // [A][O]
                                                 float* __restrict__ out) {     // [P][A*O]
    int w = blockIdx.x * 4 + (threadIdx.x >> 6);
    int lane = threadIdx.x & 63;
    int a = w >> 11;    // / P_
    int p = w & (P_ - 1);
    const bf16* hrow = Hb + ((size_t)a * P_ + p) * H_;
    float hv[16];
    float s = 0.f, ss = 0.f;
#pragma unroll
    for (int i = 0; i < 16; i++) {
        float v = __bfloat162float(hrow[lane + i * 64]);
        hv[i] = v;
        s += v;
        ss += v * v;
    }
#pragma unroll
    for (int off = 32; off; off >>= 1) {
        s += __shfl_xor(s, off);
        ss += __shfl_xor(ss, off);
    }
    float mu = s * (1.f / H_);
    float var = ss * (1.f / H_) - mu * mu;
    float rstd = rsqrtf(var + EPS_);
    const float* g = gamma + (size_t)a * H_;
    const float* be = beta + (size_t)a * H_;
    const float4* w4 = (const float4*)(W4 + (size_t)a * H_ * O_);
    float a0 = 0.f, a1 = 0.f, a2 = 0.f, a3 = 0.f;
#pragma unroll
    for (int i = 0; i < 16; i++) {
        int k = lane + i * 64;
        float hn = (hv[i] - mu) * rstd * g[k] + be[k];
        float4 wv = w4[k];
        a0 += hn * wv.x;
        a1 += hn * wv.y;
        a2 += hn * wv.z;
        a3 += hn * wv.w;
    }
#pragma unroll
    for (int off = 32; off; off >>= 1) {
        a0 += __shfl_xor(a0, off);
        a1 += __shfl_xor(a1, off);
        a2 += __shfl_xor(a2, off);
        a3 += __shfl_xor(a3, off);
    }
    if (lane < 4) {
        float v = (lane == 0 ? a0 : lane == 1 ? a1 : lane == 2 ? a2 : a3) + b4[a * O_ + lane];
        out[(size_t)p * (A_ * O_) + a * O_ + lane] = v;
    }
}

extern "C" void kernel_launch(void* const* d_in, const int* in_sizes, int n_in,
                              void* d_out, int out_size, void* d_ws, size_t ws_size,
                              hipStream_t stream) {
    const float* X     = (const float*)d_in[0];
    const float* X1    = (const float*)d_in[1];
    const float* W1    = (const float*)d_in[2];
    const float* b1    = (const float*)d_in[3];
    const float* W2    = (const float*)d_in[4];
    const float* b2    = (const float*)d_in[5];
    const float* W3    = (const float*)d_in[6];
    const float* b3    = (const float*)d_in[7];
    const float* gamma = (const float*)d_in[8];
    const float* beta  = (const float*)d_in[9];
    const float* W4    = (const float*)d_in[10];
    const float* b4    = (const float*)d_in[11];
    const int* pos     = (const int*)d_in[12];
    float* out = (float*)d_out;

    char* ws = (char*)d_ws;
    bf16* XX   = (bf16*)(ws);                          // P*2H bf16   = 8 MB
    bf16* Z    = (bf16*)(ws + ((size_t)8 << 20));      // A*P*H bf16  = 64 MB
    bf16* WT3  = (bf16*)(ws + ((size_t)72 << 20));     // A*H*H bf16  = 32 MB
    bf16* WT12 = (bf16*)(ws + ((size_t)104 << 20));    // A*H*2H bf16 = 64 MB (dead after gemm1)
    float* b12 = (float*)(ws + ((size_t)168 << 20));   // A*H fp32    = 64 KB
    bf16* Hb   = WT12;                                 // alias: written by gemm2 after WT12 is dead

    addbias_k<<<(A_ * H_ + 255) / 256, 256, 0, stream>>>(b1, b2, b12, A_ * H_);
    gather_k<<<P_, 256, 0, stream>>>(X, X1, pos, XX);
    dim3 tgrid(H_ / 64, H_ / 64, 3 * A_);
    transpose3_k<<<tgrid, 256, 0, stream>>>(W1, W2, W3, WT12, WT3);

    dim3 g1(P_ / 128, H_ / 128, A_);
    // z = [X|X1] @ [W1;W2]^T + (b1+b2)   (K = 2H, A-matrix shared across a)
    gemm_bt<false><<<g1, 256, 0, stream>>>(XX, 0, WT12, b12, Z, P_, H_, 2 * H_);
    // h = relu(z @ W3^T + b3)            (K = H, A-matrix batched over a)
    gemm_bt<true><<<g1, 256, 0, stream>>>(Z, (size_t)P_ * H_, WT3, b3, Hb, P_, H_, H_);

    ln_head_k<<<P_ * A_ / 4, 256, 0, stream>>>(Hb, gamma, beta, W4, b4, out);
}

// Round 3
// 527.291 us; speedup vs baseline: 1.0449x; 1.0429x over previous
//
#include <hip/hip_runtime.h>
#include <hip/hip_bf16.h>

using bf16 = __hip_bfloat16;
typedef __bf16 v8bf __attribute__((ext_vector_type(8)));
typedef float v4f __attribute__((ext_vector_type(4)));

#define H_ 1024
#define A_ 16
#define O_ 4
#define B_ 4096
#define P_ 2048
#define EPS_ 1e-5f

// async global->LDS, 16B per lane; lds pointer must be wave-uniform base.
__device__ __forceinline__ void gl_lds16(const void* g, void* l) {
    __builtin_amdgcn_global_load_lds(
        (const __attribute__((address_space(1))) void*)g,
        (__attribute__((address_space(3))) void*)l, 16, 0, 0);
}

// ---- b12 = b1 + b2 -------------------------------------------------------
__global__ void addbias_k(const float* __restrict__ b1, const float* __restrict__ b2,
                          float* __restrict__ b12, int n) {
    int i = blockIdx.x * 256 + threadIdx.x;
    if (i < n) b12[i] = b1[i] + b2[i];
}

// ---- gather selected rows of X,X1 -> XX[p][0:H]=X, [H:2H]=X1 (bf16) ------
__global__ __launch_bounds__(256) void gather_k(const float* __restrict__ X,
                                                const float* __restrict__ X1,
                                                const int* __restrict__ pos,
                                                bf16* __restrict__ XX) {
    int p = blockIdx.x;
    int row = pos[p];
    const float4* x  = (const float4*)(X  + (size_t)row * H_);
    const float4* x1 = (const float4*)(X1 + (size_t)row * H_);
    bf16* o = XX + (size_t)p * (2 * H_);
    int i = threadIdx.x;  // 0..255, H/4 = 256
    float4 v = x[i];
    __align__(8) bf16 t[4];
    t[0] = __float2bfloat16(v.x); t[1] = __float2bfloat16(v.y);
    t[2] = __float2bfloat16(v.z); t[3] = __float2bfloat16(v.w);
    *(uint2*)(o + i * 4) = *(const uint2*)t;
    float4 w = x1[i];
    t[0] = __float2bfloat16(w.x); t[1] = __float2bfloat16(w.y);
    t[2] = __float2bfloat16(w.z); t[3] = __float2bfloat16(w.w);
    *(uint2*)(o + H_ + i * 4) = *(const uint2*)t;
}

// ---- merged transpose+convert for W1,W2,W3 --------------------------------
__global__ __launch_bounds__(256) void transpose3_k(const float* __restrict__ W1s,
                                                    const float* __restrict__ W2s,
                                                    const float* __restrict__ W3s,
                                                    bf16* __restrict__ WT12,
                                                    bf16* __restrict__ WT3) {
    __shared__ float tile[64][65];
    const int which = blockIdx.z >> 4;
    const int a = blockIdx.z & 15;
    const float* src = (which == 0) ? W1s : (which == 1) ? W2s : W3s;
    bf16* dstBase = (which == 2) ? WT3 : WT12;
    const int dstK = (which == 2) ? H_ : 2 * H_;
    const int kOff = (which == 1) ? H_ : 0;

    const int k0 = blockIdx.x * 64;
    const int n0 = blockIdx.y * 64;
    const float* s = src + (size_t)a * H_ * H_;
    const int tc = threadIdx.x & 15;   // float4 column
    const int tr = threadIdx.x >> 4;   // 0..15
#pragma unroll
    for (int r = 0; r < 64; r += 16) {
        float4 v = *(const float4*)(s + (size_t)(k0 + tr + r) * H_ + n0 + tc * 4);
        tile[tr + r][tc * 4 + 0] = v.x;
        tile[tr + r][tc * 4 + 1] = v.y;
        tile[tr + r][tc * 4 + 2] = v.z;
        tile[tr + r][tc * 4 + 3] = v.w;
    }
    __syncthreads();
    bf16* d = dstBase + (size_t)a * H_ * dstK + kOff;
    const int wc = threadIdx.x & 7;   // k-chunk of 8
    const int wr = threadIdx.x >> 3;  // 0..31
#pragma unroll
    for (int r = 0; r < 64; r += 32) {
        const int n = wr + r;
        __align__(16) bf16 tmp[8];
#pragma unroll
        for (int j = 0; j < 8; j++) tmp[j] = __float2bfloat16(tile[wc * 8 + j][n]);
        *(uint4*)(d + (size_t)(n0 + n) * dstK + k0 + wc * 8) = *(const uint4*)tmp;
    }
}

// ---- bf16 GEMM, XCD-swizzled grid + double-buffered LDS pipeline ----------
// C[a][M][N] = A[a][M][K] @ Bt[a][N][K]^T + bias.
// Grid MUST be (16, 8, 16) linear order; blocks remapped so each XCD keeps
// one B-tile L2-resident across its 16 consecutive bm-blocks.
// LDS 16B-chunk XOR swizzle: slot (r,c) holds global chunk c ^ ((r>>1)&3).
template <bool RELU>
__global__ __launch_bounds__(256) void gemm_bt(const bf16* __restrict__ Amat, size_t aStrideA,
                                               const bf16* __restrict__ Bt,
                                               const float* __restrict__ bias,
                                               bf16* __restrict__ C,
                                               int M, int N, int K) {
    constexpr int BM = 128, BN = 128, BK = 32;
    __shared__ __align__(16) unsigned short As[2 * BM * BK];
    __shared__ __align__(16) unsigned short Bs[2 * BN * BK];

    // ---- XCD swizzle: linear id L -> (bm, bn, a) ----
    const int L = blockIdx.x + 16 * blockIdx.y + 128 * blockIdx.z;  // dispatch order
    const int xcd = L & 7;
    const int g = L >> 3;            // per-XCD sequence 0..255
    const int bm = g & 15;           // bm fastest within XCD
    const int bna = xcd + 8 * (g >> 4);  // 0..127; all XCDs share (bm, a) phase
    const int bn = bna & 7;
    const int a = bna >> 3;

    const bf16* Ab = Amat + (size_t)a * aStrideA;
    const bf16* Bb = Bt + (size_t)a * (size_t)N * K;
    const int tid = threadIdx.x;
    const int lane = tid & 63;
    const int wave = tid >> 6;
    const int wm = (wave & 1) * 64;  // wave 2x2 grid over 128x128 tile
    const int wn = (wave >> 1) * 64;

    v4f acc[4][4];
#pragma unroll
    for (int i = 0; i < 4; i++)
#pragma unroll
        for (int j = 0; j < 4; j++) acc[i][j] = (v4f){0.f, 0.f, 0.f, 0.f};

    // staging: lane's fixed LDS slot = row r0, chunk (tid&3); loads the
    // swizzled global chunk so slot c holds global chunk c ^ ((r0>>1)&3).
    const int r0 = tid >> 2;
    const int cs = (((tid & 3) ^ ((r0 >> 1) & 3))) * 8;
    const bf16* agBase = Ab + (size_t)(bm * BM + r0) * K + cs;
    const bf16* bgBase = Bb + (size_t)(bn * BN + r0) * K + cs;
    const size_t rowSkip = (size_t)64 * K;
    const int w512 = wave * 512;

    const int lr = lane & 15;
    const int q = lane >> 4;
    const int kq = (q ^ ((lr >> 1) & 3)) * 8;  // swizzled read chunk

    const int nk = K / BK;

    // prologue: stage kt=0 into buffer 0
    {
        unsigned short* aB = As;  // buf 0
        unsigned short* bB = Bs;
        gl_lds16(agBase, aB + w512);
        gl_lds16(agBase + rowSkip, aB + 2048 + w512);
        gl_lds16(bgBase, bB + w512);
        gl_lds16(bgBase + rowSkip, bB + 2048 + w512);
    }

    for (int kt = 0; kt < nk; ++kt) {
        __syncthreads();  // drains vmcnt -> buf[kt&1] tiles ready
        if (kt + 1 < nk) {
            const int k0 = (kt + 1) * BK;
            unsigned short* aB = As + ((kt + 1) & 1) * 4096;
            unsigned short* bB = Bs + ((kt + 1) & 1) * 4096;
            gl_lds16(agBase + k0, aB + w512);
            gl_lds16(agBase + k0 + rowSkip, aB + 2048 + w512);
            gl_lds16(bgBase + k0, bB + w512);
            gl_lds16(bgBase + k0 + rowSkip, bB + 2048 + w512);
        }
        const unsigned short* Ar = As + (kt & 1) * 4096;
        const unsigned short* Br = Bs + (kt & 1) * 4096;
        v8bf af[4], bfr[4];
#pragma unroll
        for (int mi = 0; mi < 4; mi++)
            af[mi] = *(const v8bf*)(Ar + (wm + mi * 16 + lr) * BK + kq);
#pragma unroll
        for (int ni = 0; ni < 4; ni++)
            bfr[ni] = *(const v8bf*)(Br + (wn + ni * 16 + lr) * BK + kq);
#pragma unroll
        for (int mi = 0; mi < 4; mi++)
#pragma unroll
            for (int ni = 0; ni < 4; ni++)
                acc[mi][ni] = __builtin_amdgcn_mfma_f32_16x16x32_bf16(af[mi], bfr[ni],
                                                                      acc[mi][ni], 0, 0, 0);
    }

    // epilogue: C/D layout col=lane&15, row=(lane>>4)*4+reg
    const int lq = lane >> 4;
    bf16* Cb = C + (size_t)a * M * N;
#pragma unroll
    for (int ni = 0; ni < 4; ni++) {
        const int col = bn * BN + wn + ni * 16 + lr;
        const float bv = bias[(size_t)a * N + col];
#pragma unroll
        for (int mi = 0; mi < 4; mi++) {
            const int row0 = bm * BM + wm + mi * 16 + lq * 4;
#pragma unroll
            for (int rg = 0; rg < 4; rg++) {
                float v = acc[mi][ni][rg] + bv;
                if (RELU) v = v > 0.f ? v : 0.f;
                Cb[(size_t)(row0 + rg) * N + col] = __float2bfloat16(v);
            }
        }
    }
}

// ---- fused LayerNorm + [H]->[O] head: one wave per (a,p) row --------------
__global__ __launch_bounds__(256) void ln_head_k(const bf16* __restrict__ Hb,  // [A][P][H]
                                                 const float* __restrict__ gamma,
                                                 const float* __restrict__ beta,
                                                 const float* __restrict__ W4,  // [A][H][O]
                                                 const float* __restrict__ b4,  // [A][O]
                                                 float* __restrict__ out) {     // [P][A*O]
    int w = blockIdx.x * 4 + (threadIdx.x >> 6);
    int lane = threadIdx.x & 63;
    int a = w >> 11;    // / P_
    int p = w & (P_ - 1);
    const bf16* hrow = Hb + ((size_t)a * P_ + p) * H_;
    float hv[16];
    float s = 0.f, ss = 0.f;
#pragma unroll
    for (int i = 0; i < 16; i++) {
        float v = __bfloat162float(hrow[lane + i * 64]);
        hv[i] = v;
        s += v;
        ss += v * v;
    }
#pragma unroll
    for (int off = 32; off; off >>= 1) {
        s += __shfl_xor(s, off);
        ss += __shfl_xor(ss, off);
    }
    float mu = s * (1.f / H_);
    float var = ss * (1.f / H_) - mu * mu;
    float rstd = rsqrtf(var + EPS_);
    const float* g = gamma + (size_t)a * H_;
    const float* be = beta + (size_t)a * H_;
    const float4* w4 = (const float4*)(W4 + (size_t)a * H_ * O_);
    float a0 = 0.f, a1 = 0.f, a2 = 0.f, a3 = 0.f;
#pragma unroll
    for (int i = 0; i < 16; i++) {
        int k = lane + i * 64;
        float hn = (hv[i] - mu) * rstd * g[k] + be[k];
        float4 wv = w4[k];
        a0 += hn * wv.x;
        a1 += hn * wv.y;
        a2 += hn * wv.z;
        a3 += hn * wv.w;
    }
#pragma unroll
    for (int off = 32; off; off >>= 1) {
        a0 += __shfl_xor(a0, off);
        a1 += __shfl_xor(a1, off);
        a2 += __shfl_xor(a2, off);
        a3 += __shfl_xor(a3, off);
    }
    if (lane < 4) {
        float v = (lane == 0 ? a0 : lane == 1 ? a1 : lane == 2 ? a2 : a3) + b4[a * O_ + lane];
        out[(size_t)p * (A_ * O_) + a * O_ + lane] = v;
    }
}

extern "C" void kernel_launch(void* const* d_in, const int* in_sizes, int n_in,
                              void* d_out, int out_size, void* d_ws, size_t ws_size,
                              hipStream_t stream) {
    const float* X     = (const float*)d_in[0];
    const float* X1    = (const float*)d_in[1];
    const float* W1    = (const float*)d_in[2];
    const float* b1    = (const float*)d_in[3];
    const float* W2    = (const float*)d_in[4];
    const float* b2    = (const float*)d_in[5];
    const float* W3    = (const float*)d_in[6];
    const float* b3    = (const float*)d_in[7];
    const float* gamma = (const float*)d_in[8];
    const float* beta  = (const float*)d_in[9];
    const float* W4    = (const float*)d_in[10];
    const float* b4    = (const float*)d_in[11];
    const int* pos     = (const int*)d_in[12];
    float* out = (float*)d_out;

    char* ws = (char*)d_ws;
    bf16* XX   = (bf16*)(ws);                          // P*2H bf16   = 8 MB
    bf16* Z    = (bf16*)(ws + ((size_t)8 << 20));      // A*P*H bf16  = 64 MB
    bf16* WT3  = (bf16*)(ws + ((size_t)72 << 20));     // A*H*H bf16  = 32 MB
    bf16* WT12 = (bf16*)(ws + ((size_t)104 << 20));    // A*H*2H bf16 = 64 MB (dead after gemm1)
    float* b12 = (float*)(ws + ((size_t)168 << 20));   // A*H fp32    = 64 KB
    bf16* Hb   = WT12;                                 // alias: written by gemm2 after WT12 is dead

    addbias_k<<<(A_ * H_ + 255) / 256, 256, 0, stream>>>(b1, b2, b12, A_ * H_);
    gather_k<<<P_, 256, 0, stream>>>(X, X1, pos, XX);
    dim3 tgrid(H_ / 64, H_ / 64, 3 * A_);
    transpose3_k<<<tgrid, 256, 0, stream>>>(W1, W2, W3, WT12, WT3);

    dim3 g1(P_ / 128, H_ / 128, A_);
    // z = [X|X1] @ [W1;W2]^T + (b1+b2)   (K = 2H, A-matrix shared across a)
    gemm_bt<false><<<g1, 256, 0, stream>>>(XX, 0, WT12, b12, Z, P_, H_, 2 * H_);
    // h = relu(z @ W3^T + b3)            (K = H, A-matrix batched over a)
    gemm_bt<true><<<g1, 256, 0, stream>>>(Z, (size_t)P_ * H_, WT3, b3, Hb, P_, H_, H_);

    ln_head_k<<<P_ * A_ / 4, 256, 0, stream>>>(Hb, gamma, beta, W4, b4, out);
}